// Round 5
// baseline (465.940 us; speedup 1.0000x reference)
//
#include <hip/hip_runtime.h>
#include <hip/hip_fp16.h>
#include <stdint.h>

typedef unsigned int   uint32;
typedef unsigned short ushort_t;
typedef _Float16 half8    __attribute__((ext_vector_type(8)));
typedef float    floatx4  __attribute__((ext_vector_type(4)));
typedef float    floatx16 __attribute__((ext_vector_type(16)));

#define DEVINL __device__ __forceinline__

#define N_FRAGS 1184            // total 1KB weight fragments (32x32x16 layout)

// ---------------------------------------------------------------------------
// 32x32x16 f16 MFMA everywhere (was 16x16x32). Why: (1) pipe rate 2178 vs
// 1955 TF (µbench) -> ~10% less matrix-pipe time for the same FLOPs, half
// the MFMA instruction count; (2) operand register footprint halves
// (afr 16, bfr 16 vs 32/32), which -- with bias moved from MFMA-C-init to
// the epilogue -- brings per-wave demand under the 128-reg cap needed for
// 4 blocks/CU (round-4 math: matrix pipe busy 55% == MfmaUtil, need more
// resident waves to cover the other 45%).
//
// Operand lane maps (m74/m101-verified C/D; A/B by the standard CDNA scaling
// of the working 16x16x32 kernel):
//   A (weights): lane l holds W[k = kt*16 + (l>>5)*8 + e][n = nt*32 + (l&31)]
//   B (acts):    lane l holds h[m = rt*32 + (l&31)][k = kt*16 + (l>>5)*8 + e]
//   D:           lane l, reg r = D[n = (r&3)+8*(r>>2)+4*(l>>5)][m = l&31]
//
// Fragment-major LDS layout (conflict-free stride-1 b128 B-reads, kept from
// round 4): element h[row][f] at
//   off(row,f) = (f>>4)*1024 + (row>>5)*512 + (((f>>3)&1)*32 + (row&31))*8 + (f&7)
// ---------------------------------------------------------------------------
DEVINL int fragoff(int row, int f) {
    return (f >> 4)*1024 + (row >> 5)*512
         + ((((f >> 3) & 1) << 5) + (row & 31))*8 + (f & 7);
}

// Packed f16 weight fragments in module-owned device memory. Rewritten every
// launch from restored fp32 inputs -> graph-capture safe. L2-resident.
__device__ __align__(16) ushort_t g_ws[(size_t)N_FRAGS * 512];

DEVINL ushort_t f2h_u(float v) { return __half_as_ushort(__float2half(v)); }

// ---------------------------------------------------------------------------
// A-fragment pack: lane (s=l>>5, c=l&31) holds W[k=kt*16+s*8+j][n=nt*32+c].
// skip63 (layer-4 concat): k<63 -> row k, k==63 -> 0, k>63 -> row k-1.
// ---------------------------------------------------------------------------
DEVINL uint4 make_frag_qword(const float* __restrict__ W, int Kr, int Nr,
                             int skip63, int kt, int nt, int s, int c)
{
    const int n = nt*32 + c;
    uint32 pk[4];
    #pragma unroll
    for (int jj = 0; jj < 4; ++jj) {
        ushort_t h2[2];
        #pragma unroll
        for (int e = 0; e < 2; ++e) {
            const int k = kt*16 + s*8 + jj*2 + e;
            float v = 0.f;
            if (n < Nr) {
                if (skip63) {
                    if (k != 63) { const int rr = (k < 63) ? k : (k - 1); v = W[(size_t)rr*Nr + n]; }
                } else if (k < Kr) {
                    v = W[(size_t)k*Nr + n];
                }
            }
            h2[e] = f2h_u(v);
        }
        pk[jj] = (uint32)h2[0] | ((uint32)h2[1] << 16);
    }
    return make_uint4(pk[0], pk[1], pk[2], pk[3]);
}

// frag layout per layer: index = kt*NT + nt (kt-major). Per-layer frag counts:
// L0 4x8=32, L1-7/fin 16x8=128 (L4 20x8=160), sigma 16x1, rgb1 18x4=72,
// rgb2 8x1. foff cumulative below.
__global__ __launch_bounds__(256) void prep_weights(
    const float* __restrict__ w0, const float* __restrict__ w1,
    const float* __restrict__ w2, const float* __restrict__ w3,
    const float* __restrict__ w4, const float* __restrict__ w5,
    const float* __restrict__ w6, const float* __restrict__ w7,
    const float* __restrict__ wf, const float* __restrict__ wsig,
    const float* __restrict__ wr1, const float* __restrict__ wr2)
{
    int gid  = blockIdx.x * 256 + threadIdx.x;
    int frag = gid >> 6;
    if (frag >= N_FRAGS) return;
    int lane = gid & 63;

    constexpr int foff[13] = {0,32,160,288,416,576,704,832,960,1088,1104,1176,1184};
    int t = 0;
    #pragma unroll
    for (int i = 1; i <= 11; ++i) if (frag >= foff[i]) t = i;

    const float* W; int fo, ntc, Kr, Nr;
    switch (t) {
        case 0:  W = w0;   fo = 0;    ntc = 8; Kr = 63;  Nr = 256; break;
        case 1:  W = w1;   fo = 32;   ntc = 8; Kr = 256; Nr = 256; break;
        case 2:  W = w2;   fo = 160;  ntc = 8; Kr = 256; Nr = 256; break;
        case 3:  W = w3;   fo = 288;  ntc = 8; Kr = 256; Nr = 256; break;
        case 4:  W = w4;   fo = 416;  ntc = 8; Kr = 319; Nr = 256; break;
        case 5:  W = w5;   fo = 576;  ntc = 8; Kr = 256; Nr = 256; break;
        case 6:  W = w6;   fo = 704;  ntc = 8; Kr = 256; Nr = 256; break;
        case 7:  W = w7;   fo = 832;  ntc = 8; Kr = 256; Nr = 256; break;
        case 8:  W = wf;   fo = 960;  ntc = 8; Kr = 256; Nr = 256; break;
        case 9:  W = wsig; fo = 1088; ntc = 1; Kr = 256; Nr = 1;   break;
        case 10: W = wr1;  fo = 1104; ntc = 4; Kr = 283; Nr = 128; break;
        default: W = wr2;  fo = 1176; ntc = 1; Kr = 128; Nr = 3;   break;
    }
    int fl = frag - fo;
    int nt = fl % ntc;
    int kt = fl / ntc;
    uint4 pk = make_frag_qword(W, Kr, Nr, (t == 4) ? 1 : 0, kt, nt,
                               lane >> 5, lane & 31);
    *(uint4*)(g_ws + (size_t)frag*512 + lane*8) = pk;
}

// ---------------------------------------------------------------------------
// Layer: D[n][m] = sum_k W[k][n] * h[m][k], 32x32x16 tiles. Wave computes
// 64 rows (rt 0..1) x NT_W*32 feats. A-frags from L2-hot g_ws, B-frags from
// fragment-major LDS (stride-1 b128); depth-1 pipelined. kt==0 uses a zero
// C-operand (bias moved to epilogue: frees the 32-reg binit that would
// break the 128-reg/4-block budget).
// ---------------------------------------------------------------------------
template <int NT_W, int KT, int KT_SPLIT, int NTT>
DEVINL void run_layer(const ushort_t* __restrict__ wsrc,
                      const ushort_t* __restrict__ in0,
                      const ushort_t* __restrict__ in1,
                      int lane, int nt_lo, floatx16 (&acc)[2][NT_W])
{
    half8 bfr[2][2];
    half8 afr[2][NT_W];
    const floatx16 vz = {0.f,0.f,0.f,0.f, 0.f,0.f,0.f,0.f,
                         0.f,0.f,0.f,0.f, 0.f,0.f,0.f,0.f};

    auto loadk = [&](int kt, int buf) {
        const ushort_t* bb = ((kt < KT_SPLIT) ? in0 + kt*1024
                                              : in1 + (kt - KT_SPLIT)*1024) + lane*8;
        #pragma unroll
        for (int rt = 0; rt < 2; ++rt)
            bfr[buf][rt] = *(const half8*)(bb + rt*512);
        const ushort_t* wb = wsrc + (size_t)(kt*NTT + nt_lo)*512 + lane*8;
        #pragma unroll
        for (int nt = 0; nt < NT_W; ++nt)
            afr[buf][nt] = *(const half8*)(wb + nt*512);
    };

    loadk(0, 0);
    #pragma unroll
    for (int kt = 0; kt < KT; ++kt) {
        const int cur = kt & 1;
        if (kt + 1 < KT) loadk(kt + 1, cur ^ 1);
        #pragma unroll
        for (int nt = 0; nt < NT_W; ++nt)
            #pragma unroll
            for (int rt = 0; rt < 2; ++rt)
                acc[rt][nt] = __builtin_amdgcn_mfma_f32_32x32x16_f16(
                    afr[cur][nt], bfr[cur][rt],
                    (kt == 0) ? vz : acc[rt][nt], 0, 0, 0);
    }
}

// epilogue: bias add (+optional relu), pack to f16, store into frag-major LDS.
// Lane l reg r holds D[n = n0+(r&3)+8*(r>>2)+4*s][m = rt*32+c], s=l>>5, c=l&31.
// bias quads: q[p][j] = b[n0+8p+4s+j] -> v(r) += q[r>>2][r&3].
// Store as b64 per r4-group (r4,r4+1,r4+2,r4+3 share a 4-half run):
//   dst = ((n0>>4)+(r4>>3))*1024 + rt*512 + (((r4>>2)&1)*32 + c)*8 + 4*s
// (~4-way bank conflict on the write side; LDS pipe has headroom -- r4 data.)
template <int NT_W, bool RELU>
DEVINL void epilogue32(floatx16 (&acc)[2][NT_W], int nt_lo,
                       ushort_t* __restrict__ dsth, const float* __restrict__ bias,
                       int lane)
{
    const int s = lane >> 5, c = lane & 31;
    #pragma unroll
    for (int nt = 0; nt < NT_W; ++nt) {
        const int n0 = (nt_lo + nt)*32;
        floatx4 q[4];
        #pragma unroll
        for (int p = 0; p < 4; ++p)
            q[p] = *(const floatx4*)(bias + n0 + 8*p + 4*s);
        #pragma unroll
        for (int rt = 0; rt < 2; ++rt) {
            #pragma unroll
            for (int r4 = 0; r4 < 16; r4 += 4) {
                float v0 = acc[rt][nt][r4+0] + q[r4>>2][0];
                float v1 = acc[rt][nt][r4+1] + q[r4>>2][1];
                float v2 = acc[rt][nt][r4+2] + q[r4>>2][2];
                float v3 = acc[rt][nt][r4+3] + q[r4>>2][3];
                if (RELU) {
                    v0 = fmaxf(v0, 0.f); v1 = fmaxf(v1, 0.f);
                    v2 = fmaxf(v2, 0.f); v3 = fmaxf(v3, 0.f);
                }
                uint2 u;
                u.x = __builtin_bit_cast(uint32, __builtin_amdgcn_cvt_pkrtz(v0, v1));
                u.y = __builtin_bit_cast(uint32, __builtin_amdgcn_cvt_pkrtz(v2, v3));
                const int dst = ((nt_lo + nt)*2 + (r4 >> 3))*1024 + rt*512
                              + ((((r4 >> 2) & 1) << 5) + c)*8 + 4*s;
                *(uint2*)(dsth + dst) = u;
            }
        }
    }
}

// (256,4): 128-reg/wave cap -> 4 blocks/CU (LDS 40KB/block: shh 32KB +
// shx 8KB, dir-posenc overlaid into shx after layer 4 frees it). Demand est:
// acc 64 + afr 16 + bfr 16 + zeros/addr ~25 ≈ 120. 16 waves/CU = 4/SIMD
// (was 3/SIMD at 54% MfmaUtil == exactly the 3-wave matrix-pipe share).
__global__ __launch_bounds__(256, 4) void nerf_fused(
    const float* __restrict__ x,
    const float* __restrict__ b0, const float* __restrict__ b1,
    const float* __restrict__ b2, const float* __restrict__ b3,
    const float* __restrict__ b4, const float* __restrict__ b5,
    const float* __restrict__ b6, const float* __restrict__ b7,
    const float* __restrict__ bf, const float* __restrict__ bsig,
    const float* __restrict__ br1, const float* __restrict__ br2,
    float* __restrict__ out)
{
    __shared__ __align__(16) ushort_t shh[16*1024];  // h acts, frag-major, 32KB
    __shared__ __align__(16) ushort_t shx[4*1024];   // xyz posenc 8KB; kb0-1
                                                     // reused for dir after L4
    ushort_t* shd = shx;                             // dir overlay (4KB)

    const int tid  = threadIdx.x;
    const int wave = tid >> 6, lane = tid & 63;
    const int r0 = blockIdx.x * 64;
    const ushort_t* ws = g_ws;
    const int nt_lo2 = wave * 2;

    // ---- xyz positional encoding only (row = lane, job-set = wave) ----
    {
        const int r = lane;
        const float* xr = x + (size_t)(r0 + r)*6;
        for (int j = wave; j < 30; j += 4) {      // xyz: F=10, 3 + f*6 + s*3 + a
            int f = j/3, a = j%3;
            float v = xr[a] * (float)(1 << f);
            shx[fragoff(r, 3 + f*6 + a)]     = f2h_u(sinf(v));
            shx[fragoff(r, 3 + f*6 + 3 + a)] = f2h_u(cosf(v));
        }
        if (wave == 0) {
            #pragma unroll
            for (int a = 0; a < 3; ++a) shx[fragoff(r, a)] = f2h_u(xr[a]);
            shx[fragoff(r, 63)] = 0;              // k-pad must be 0
        }
    }
    __syncthreads();

    const float* BS[8] = {b0,b1,b2,b3,b4,b5,b6,b7};
    const int WO[8] = {0,16384,81920,147456,212992,294912,360448,425984};

    floatx16 acc[2][2];

    // layer 0: 64(xyz) -> 256
    run_layer<2,4,4,8>(ws + WO[0], shx, shx, lane, nt_lo2, acc);
    __syncthreads();
    epilogue32<2,true>(acc, nt_lo2, shh, b0, lane);
    __syncthreads();

    // layers 1..7 (layer 4 = skip-concat: 4 kt from xyz, 16 kt from h)
    #pragma unroll
    for (int l = 1; l < 8; ++l) {
        if (l == 4)
            run_layer<2,20,4,8>(ws + WO[4], shx, shh, lane, nt_lo2, acc);
        else
            run_layer<2,16,16,8>(ws + WO[l], shh, shh, lane, nt_lo2, acc);
        __syncthreads();   // all waves done reading before overwrites
        if (l == 4) {
            // shx now dead: compute dir posenc into its first 2 kb (saves
            // 4KB LDS -> the 4th block/CU). Runs alongside the epilogue,
            // visibility covered by the next barrier.
            const int r = lane;
            const float* xr = x + (size_t)(r0 + r)*6;
            for (int j = wave; j < 12; j += 4) {  // dir: F=4
                int f = j/3, a = j%3;
                float v = xr[3+a] * (float)(1 << f);
                shd[fragoff(r, 3 + f*6 + a)]     = f2h_u(sinf(v));
                shd[fragoff(r, 3 + f*6 + 3 + a)] = f2h_u(cosf(v));
            }
            if (wave == 0) {
                #pragma unroll
                for (int a = 0; a < 3; ++a) shd[fragoff(r, a)] = f2h_u(xr[3+a]);
                #pragma unroll
                for (int kq = 27; kq < 32; ++kq) shd[fragoff(r, kq)] = 0;
            }
        }
        epilogue32<2,true>(acc, nt_lo2, shh, BS[l], lane);
        __syncthreads();
    }

    // sigma head: wave 0 only (barrier-free region, overlaps others' final).
    // Output feature 0 = reg 0, lanes 0..31 (n = (r&3)+8*(r>>2)+4*s == 0).
    if (wave == 0) {
        floatx16 sacc[2][1];
        run_layer<1,16,16,1>(ws + 557056, shh, shh, lane, 0, sacc);
        if (lane < 32) {
            const float bs_ = bsig[0];
            #pragma unroll
            for (int rt = 0; rt < 2; ++rt)
                out[(size_t)(r0 + rt*32 + lane)*4 + 3] = sacc[rt][0][0] + bs_;
        }
    }

    // final: 256 -> 256, NO relu (barrier also covers in-flight sigma reads)
    run_layer<2,16,16,8>(ws + 491520, shh, shh, lane, nt_lo2, acc);
    __syncthreads();
    epilogue32<2,false>(acc, nt_lo2, shh, bf, lane);
    __syncthreads();

    // rgb1: [final(256) | dir(27->32)] -> 128, relu. NT=4, wave w owns nt=w.
    {
        floatx16 racc[2][1];
        run_layer<1,18,16,4>(ws + 565248, shh, shd, lane, wave, racc);
        __syncthreads();
        epilogue32<1,true>(racc, wave, shh, br1, lane);
        __syncthreads();
    }

    // rgb2: 128 -> 3, sigmoid, store rgb (wave 0 only). Channels = regs 0..2,
    // lanes 0..31.
    if (wave == 0) {
        floatx16 cacc[2][1];
        run_layer<1,8,8,1>(ws + 602112, shh, shh, lane, 0, cacc);
        if (lane < 32) {
            const float c0 = br2[0], c1 = br2[1], c2 = br2[2];
            #pragma unroll
            for (int rt = 0; rt < 2; ++rt) {
                const size_t o = (size_t)(r0 + rt*32 + lane)*4;
                out[o+0] = 1.f/(1.f + expf(-(cacc[rt][0][0] + c0)));
                out[o+1] = 1.f/(1.f + expf(-(cacc[rt][0][1] + c1)));
                out[o+2] = 1.f/(1.f + expf(-(cacc[rt][0][2] + c2)));
            }
        }
    }
}

extern "C" void kernel_launch(void* const* d_in, const int* in_sizes, int n_in,
                              void* d_out, int out_size, void* d_ws, size_t ws_size,
                              hipStream_t stream)
{
    const float* x  = (const float*)d_in[0];
    const float* w0 = (const float*)d_in[1];  const float* b0 = (const float*)d_in[2];
    const float* w1 = (const float*)d_in[3];  const float* b1 = (const float*)d_in[4];
    const float* w2 = (const float*)d_in[5];  const float* b2 = (const float*)d_in[6];
    const float* w3 = (const float*)d_in[7];  const float* b3 = (const float*)d_in[8];
    const float* w4 = (const float*)d_in[9];  const float* b4 = (const float*)d_in[10];
    const float* w5 = (const float*)d_in[11]; const float* b5 = (const float*)d_in[12];
    const float* w6 = (const float*)d_in[13]; const float* b6 = (const float*)d_in[14];
    const float* w7 = (const float*)d_in[15]; const float* b7 = (const float*)d_in[16];
    const float* wf = (const float*)d_in[17]; const float* bf = (const float*)d_in[18];
    const float* wsg= (const float*)d_in[19]; const float* bsg= (const float*)d_in[20];
    const float* wr1= (const float*)d_in[21]; const float* br1= (const float*)d_in[22];
    const float* wr2= (const float*)d_in[23]; const float* br2= (const float*)d_in[24];
    float* out = (float*)d_out;
    const int N = in_sizes[0] / 6;

    prep_weights<<<(N_FRAGS*64 + 255)/256, 256, 0, stream>>>(
        w0,w1,w2,w3,w4,w5,w6,w7,wf,wsg,wr1,wr2);
    nerf_fused<<<N/64, 256, 0, stream>>>(
        x, b0,b1,b2,b3,b4,b5,b6,b7, bf,bsg, br1,br2, out);
}

// Round 6
// 456.689 us; speedup vs baseline: 1.0203x; 1.0203x over previous
//
#include <hip/hip_runtime.h>
#include <hip/hip_fp16.h>
#include <stdint.h>

typedef unsigned int   uint32;
typedef unsigned short ushort_t;
typedef _Float16 half8    __attribute__((ext_vector_type(8)));
typedef float    floatx4  __attribute__((ext_vector_type(4)));
typedef float    floatx16 __attribute__((ext_vector_type(16)));

#define DEVINL __device__ __forceinline__

#define N_FRAGS 1184            // total 1KB weight fragments (32x32x16 layout)

// ---------------------------------------------------------------------------
// 32x32x16 f16 MFMA everywhere. Why vs 16x16x32: pipe rate 2178 vs 1955 TF
// (µbench m23/m64) -> ~10% less matrix-pipe time for the same FLOPs, and
// half the MFMA instruction count (frees issue slots).
//
// Occupancy: (256,3). The 64-row x 256-feat block needs 64 f32 acc regs per
// thread; total demand ~150. A 128-reg cap (4 blk/CU) ALWAYS spills -- proven
// twice (r1: 294MB scratch writes, r5: 277MB). 3 blocks/CU inter-block
// overlap is this kernel's latency hiding (r2: 1 block/CU -> 35% MfmaUtil).
//
// Operand lane maps (r5-verified end-to-end, absmax unchanged):
//   A (weights): lane l holds W[k = kt*16 + (l>>5)*8 + e][n = nt*32 + (l&31)]
//   B (acts):    lane l holds h[m = rt*32 + (l&31)][k = kt*16 + (l>>5)*8 + e]
//   D:           lane l, reg r = D[n = (r&3)+8*(r>>2)+4*(l>>5)][m = l&31]
//
// Fragment-major LDS layout (conflict-free stride-1 b128 B-reads, r4):
//   off(row,f) = (f>>4)*1024 + (row>>5)*512 + (((f>>3)&1)*32 + (row&31))*8 + (f&7)
// ---------------------------------------------------------------------------
DEVINL int fragoff(int row, int f) {
    return (f >> 4)*1024 + (row >> 5)*512
         + ((((f >> 3) & 1) << 5) + (row & 31))*8 + (f & 7);
}

// Packed f16 weight fragments in module-owned device memory. Rewritten every
// launch from restored fp32 inputs -> graph-capture safe. L2-resident.
__device__ __align__(16) ushort_t g_ws[(size_t)N_FRAGS * 512];

DEVINL ushort_t f2h_u(float v) { return __half_as_ushort(__float2half(v)); }

// ---------------------------------------------------------------------------
// A-fragment pack: lane (s=l>>5, c=l&31) holds W[k=kt*16+s*8+j][n=nt*32+c].
// skip63 (layer-4 concat): k<63 -> row k, k==63 -> 0, k>63 -> row k-1.
// ---------------------------------------------------------------------------
DEVINL uint4 make_frag_qword(const float* __restrict__ W, int Kr, int Nr,
                             int skip63, int kt, int nt, int s, int c)
{
    const int n = nt*32 + c;
    uint32 pk[4];
    #pragma unroll
    for (int jj = 0; jj < 4; ++jj) {
        ushort_t h2[2];
        #pragma unroll
        for (int e = 0; e < 2; ++e) {
            const int k = kt*16 + s*8 + jj*2 + e;
            float v = 0.f;
            if (n < Nr) {
                if (skip63) {
                    if (k != 63) { const int rr = (k < 63) ? k : (k - 1); v = W[(size_t)rr*Nr + n]; }
                } else if (k < Kr) {
                    v = W[(size_t)k*Nr + n];
                }
            }
            h2[e] = f2h_u(v);
        }
        pk[jj] = (uint32)h2[0] | ((uint32)h2[1] << 16);
    }
    return make_uint4(pk[0], pk[1], pk[2], pk[3]);
}

// frag layout per layer: index = kt*NT + nt (kt-major). Per-layer frag counts:
// L0 4x8=32, L1-7/fin 16x8=128 (L4 20x8=160), sigma 16x1, rgb1 18x4=72,
// rgb2 8x1. foff cumulative below.
__global__ __launch_bounds__(256) void prep_weights(
    const float* __restrict__ w0, const float* __restrict__ w1,
    const float* __restrict__ w2, const float* __restrict__ w3,
    const float* __restrict__ w4, const float* __restrict__ w5,
    const float* __restrict__ w6, const float* __restrict__ w7,
    const float* __restrict__ wf, const float* __restrict__ wsig,
    const float* __restrict__ wr1, const float* __restrict__ wr2)
{
    int gid  = blockIdx.x * 256 + threadIdx.x;
    int frag = gid >> 6;
    if (frag >= N_FRAGS) return;
    int lane = gid & 63;

    constexpr int foff[13] = {0,32,160,288,416,576,704,832,960,1088,1104,1176,1184};
    int t = 0;
    #pragma unroll
    for (int i = 1; i <= 11; ++i) if (frag >= foff[i]) t = i;

    const float* W; int fo, ntc, Kr, Nr;
    switch (t) {
        case 0:  W = w0;   fo = 0;    ntc = 8; Kr = 63;  Nr = 256; break;
        case 1:  W = w1;   fo = 32;   ntc = 8; Kr = 256; Nr = 256; break;
        case 2:  W = w2;   fo = 160;  ntc = 8; Kr = 256; Nr = 256; break;
        case 3:  W = w3;   fo = 288;  ntc = 8; Kr = 256; Nr = 256; break;
        case 4:  W = w4;   fo = 416;  ntc = 8; Kr = 319; Nr = 256; break;
        case 5:  W = w5;   fo = 576;  ntc = 8; Kr = 256; Nr = 256; break;
        case 6:  W = w6;   fo = 704;  ntc = 8; Kr = 256; Nr = 256; break;
        case 7:  W = w7;   fo = 832;  ntc = 8; Kr = 256; Nr = 256; break;
        case 8:  W = wf;   fo = 960;  ntc = 8; Kr = 256; Nr = 256; break;
        case 9:  W = wsig; fo = 1088; ntc = 1; Kr = 256; Nr = 1;   break;
        case 10: W = wr1;  fo = 1104; ntc = 4; Kr = 283; Nr = 128; break;
        default: W = wr2;  fo = 1176; ntc = 1; Kr = 128; Nr = 3;   break;
    }
    int fl = frag - fo;
    int nt = fl % ntc;
    int kt = fl / ntc;
    uint4 pk = make_frag_qword(W, Kr, Nr, (t == 4) ? 1 : 0, kt, nt,
                               lane >> 5, lane & 31);
    *(uint4*)(g_ws + (size_t)frag*512 + lane*8) = pk;
}

// ---------------------------------------------------------------------------
// Layer: D[n][m] = sum_k W[k][n] * h[m][k], 32x32x16 tiles. Wave computes
// 64 rows (rt 0..1) x NT_W*32 feats. A-frags from L2-hot g_ws, B-frags from
// fragment-major LDS (stride-1 b128); depth-1 pipelined. kt==0 uses a zero
// C-operand; bias is added in the epilogue (cheaper reg-wise than binit).
// ---------------------------------------------------------------------------
template <int NT_W, int KT, int KT_SPLIT, int NTT>
DEVINL void run_layer(const ushort_t* __restrict__ wsrc,
                      const ushort_t* __restrict__ in0,
                      const ushort_t* __restrict__ in1,
                      int lane, int nt_lo, floatx16 (&acc)[2][NT_W])
{
    half8 bfr[2][2];
    half8 afr[2][NT_W];
    const floatx16 vz = {0.f,0.f,0.f,0.f, 0.f,0.f,0.f,0.f,
                         0.f,0.f,0.f,0.f, 0.f,0.f,0.f,0.f};

    auto loadk = [&](int kt, int buf) {
        const ushort_t* bb = ((kt < KT_SPLIT) ? in0 + kt*1024
                                              : in1 + (kt - KT_SPLIT)*1024) + lane*8;
        #pragma unroll
        for (int rt = 0; rt < 2; ++rt)
            bfr[buf][rt] = *(const half8*)(bb + rt*512);
        const ushort_t* wb = wsrc + (size_t)(kt*NTT + nt_lo)*512 + lane*8;
        #pragma unroll
        for (int nt = 0; nt < NT_W; ++nt)
            afr[buf][nt] = *(const half8*)(wb + nt*512);
    };

    loadk(0, 0);
    #pragma unroll
    for (int kt = 0; kt < KT; ++kt) {
        const int cur = kt & 1;
        if (kt + 1 < KT) loadk(kt + 1, cur ^ 1);
        #pragma unroll
        for (int nt = 0; nt < NT_W; ++nt)
            #pragma unroll
            for (int rt = 0; rt < 2; ++rt)
                acc[rt][nt] = __builtin_amdgcn_mfma_f32_32x32x16_f16(
                    afr[cur][nt], bfr[cur][rt],
                    (kt == 0) ? vz : acc[rt][nt], 0, 0, 0);
    }
}

// epilogue: bias add (+optional relu), pack to f16, store into frag-major LDS.
// Lane l reg r holds D[n = n0+(r&3)+8*(r>>2)+4*s][m = rt*32+c], s=l>>5, c=l&31.
// bias quads: q[p][j] = b[n0+8p+4s+j] -> v(r) += q[r>>2][r&3].
// Store as b64 per r4-group:
//   dst = ((n0>>4)+(r4>>3))*1024 + rt*512 + (((r4>>2)&1)*32 + c)*8 + 4*s
template <int NT_W, bool RELU>
DEVINL void epilogue32(floatx16 (&acc)[2][NT_W], int nt_lo,
                       ushort_t* __restrict__ dsth, const float* __restrict__ bias,
                       int lane)
{
    const int s = lane >> 5, c = lane & 31;
    #pragma unroll
    for (int nt = 0; nt < NT_W; ++nt) {
        const int n0 = (nt_lo + nt)*32;
        floatx4 q[4];
        #pragma unroll
        for (int p = 0; p < 4; ++p)
            q[p] = *(const floatx4*)(bias + n0 + 8*p + 4*s);
        #pragma unroll
        for (int rt = 0; rt < 2; ++rt) {
            #pragma unroll
            for (int r4 = 0; r4 < 16; r4 += 4) {
                float v0 = acc[rt][nt][r4+0] + q[r4>>2][0];
                float v1 = acc[rt][nt][r4+1] + q[r4>>2][1];
                float v2 = acc[rt][nt][r4+2] + q[r4>>2][2];
                float v3 = acc[rt][nt][r4+3] + q[r4>>2][3];
                if (RELU) {
                    v0 = fmaxf(v0, 0.f); v1 = fmaxf(v1, 0.f);
                    v2 = fmaxf(v2, 0.f); v3 = fmaxf(v3, 0.f);
                }
                uint2 u;
                u.x = __builtin_bit_cast(uint32, __builtin_amdgcn_cvt_pkrtz(v0, v1));
                u.y = __builtin_bit_cast(uint32, __builtin_amdgcn_cvt_pkrtz(v2, v3));
                const int dst = ((nt_lo + nt)*2 + (r4 >> 3))*1024 + rt*512
                              + ((((r4 >> 2) & 1) << 5) + c)*8 + 4*s;
                *(uint2*)(dsth + dst) = u;
            }
        }
    }
}

// (256,3): 168-reg cap, demand ~150 -> no spill (the r0/r4 regime). LDS 40KB
// -> occupancy stays reg-limited at 3 blocks/CU.
__global__ __launch_bounds__(256, 3) void nerf_fused(
    const float* __restrict__ x,
    const float* __restrict__ b0, const float* __restrict__ b1,
    const float* __restrict__ b2, const float* __restrict__ b3,
    const float* __restrict__ b4, const float* __restrict__ b5,
    const float* __restrict__ b6, const float* __restrict__ b7,
    const float* __restrict__ bf, const float* __restrict__ bsig,
    const float* __restrict__ br1, const float* __restrict__ br2,
    float* __restrict__ out)
{
    __shared__ __align__(16) ushort_t shh[16*1024];  // h acts, frag-major, 32KB
    __shared__ __align__(16) ushort_t shx[4*1024];   // xyz posenc 8KB; kb0-1
                                                     // reused for dir after L4
    ushort_t* shd = shx;                             // dir overlay (4KB)

    const int tid  = threadIdx.x;
    const int wave = tid >> 6, lane = tid & 63;
    const int r0 = blockIdx.x * 64;
    const ushort_t* ws = g_ws;
    const int nt_lo2 = wave * 2;

    // ---- xyz positional encoding only (row = lane, job-set = wave) ----
    {
        const int r = lane;
        const float* xr = x + (size_t)(r0 + r)*6;
        for (int j = wave; j < 30; j += 4) {      // xyz: F=10, 3 + f*6 + s*3 + a
            int f = j/3, a = j%3;
            float v = xr[a] * (float)(1 << f);
            shx[fragoff(r, 3 + f*6 + a)]     = f2h_u(sinf(v));
            shx[fragoff(r, 3 + f*6 + 3 + a)] = f2h_u(cosf(v));
        }
        if (wave == 0) {
            #pragma unroll
            for (int a = 0; a < 3; ++a) shx[fragoff(r, a)] = f2h_u(xr[a]);
            shx[fragoff(r, 63)] = 0;              // k-pad must be 0
        }
    }
    __syncthreads();

    const float* BS[8] = {b0,b1,b2,b3,b4,b5,b6,b7};
    const int WO[8] = {0,16384,81920,147456,212992,294912,360448,425984};

    floatx16 acc[2][2];

    // layer 0: 64(xyz) -> 256
    run_layer<2,4,4,8>(ws + WO[0], shx, shx, lane, nt_lo2, acc);
    __syncthreads();
    epilogue32<2,true>(acc, nt_lo2, shh, b0, lane);
    __syncthreads();

    // layers 1..7 (layer 4 = skip-concat: 4 kt from xyz, 16 kt from h)
    #pragma unroll
    for (int l = 1; l < 8; ++l) {
        if (l == 4)
            run_layer<2,20,4,8>(ws + WO[4], shx, shh, lane, nt_lo2, acc);
        else
            run_layer<2,16,16,8>(ws + WO[l], shh, shh, lane, nt_lo2, acc);
        __syncthreads();   // all waves done reading before overwrites
        if (l == 4) {
            // shx now dead: compute dir posenc into its first kb (saves 4KB
            // LDS). Visibility covered by the next barrier.
            const int r = lane;
            const float* xr = x + (size_t)(r0 + r)*6;
            for (int j = wave; j < 12; j += 4) {  // dir: F=4
                int f = j/3, a = j%3;
                float v = xr[3+a] * (float)(1 << f);
                shd[fragoff(r, 3 + f*6 + a)]     = f2h_u(sinf(v));
                shd[fragoff(r, 3 + f*6 + 3 + a)] = f2h_u(cosf(v));
            }
            if (wave == 0) {
                #pragma unroll
                for (int a = 0; a < 3; ++a) shd[fragoff(r, a)] = f2h_u(xr[3+a]);
                #pragma unroll
                for (int kq = 27; kq < 32; ++kq) shd[fragoff(r, kq)] = 0;
            }
        }
        epilogue32<2,true>(acc, nt_lo2, shh, BS[l], lane);
        __syncthreads();
    }

    // sigma head: wave 0 only (barrier-free region, overlaps others' final).
    // Output feature 0 = reg 0, lanes 0..31 (n = (r&3)+8*(r>>2)+4*s == 0).
    if (wave == 0) {
        floatx16 sacc[2][1];
        run_layer<1,16,16,1>(ws + 557056, shh, shh, lane, 0, sacc);
        if (lane < 32) {
            const float bs_ = bsig[0];
            #pragma unroll
            for (int rt = 0; rt < 2; ++rt)
                out[(size_t)(r0 + rt*32 + lane)*4 + 3] = sacc[rt][0][0] + bs_;
        }
    }

    // final: 256 -> 256, NO relu (barrier also covers in-flight sigma reads)
    run_layer<2,16,16,8>(ws + 491520, shh, shh, lane, nt_lo2, acc);
    __syncthreads();
    epilogue32<2,false>(acc, nt_lo2, shh, bf, lane);
    __syncthreads();

    // rgb1: [final(256) | dir(27->32)] -> 128, relu. NT=4, wave w owns nt=w.
    {
        floatx16 racc[2][1];
        run_layer<1,18,16,4>(ws + 565248, shh, shd, lane, wave, racc);
        __syncthreads();
        epilogue32<1,true>(racc, wave, shh, br1, lane);
        __syncthreads();
    }

    // rgb2: 128 -> 3, sigmoid, store rgb (wave 0 only). Channels = regs 0..2,
    // lanes 0..31.
    if (wave == 0) {
        floatx16 cacc[2][1];
        run_layer<1,8,8,1>(ws + 602112, shh, shh, lane, 0, cacc);
        if (lane < 32) {
            const float c0 = br2[0], c1 = br2[1], c2 = br2[2];
            #pragma unroll
            for (int rt = 0; rt < 2; ++rt) {
                const size_t o = (size_t)(r0 + rt*32 + lane)*4;
                out[o+0] = 1.f/(1.f + expf(-(cacc[rt][0][0] + c0)));
                out[o+1] = 1.f/(1.f + expf(-(cacc[rt][0][1] + c1)));
                out[o+2] = 1.f/(1.f + expf(-(cacc[rt][0][2] + c2)));
            }
        }
    }
}

extern "C" void kernel_launch(void* const* d_in, const int* in_sizes, int n_in,
                              void* d_out, int out_size, void* d_ws, size_t ws_size,
                              hipStream_t stream)
{
    const float* x  = (const float*)d_in[0];
    const float* w0 = (const float*)d_in[1];  const float* b0 = (const float*)d_in[2];
    const float* w1 = (const float*)d_in[3];  const float* b1 = (const float*)d_in[4];
    const float* w2 = (const float*)d_in[5];  const float* b2 = (const float*)d_in[6];
    const float* w3 = (const float*)d_in[7];  const float* b3 = (const float*)d_in[8];
    const float* w4 = (const float*)d_in[9];  const float* b4 = (const float*)d_in[10];
    const float* w5 = (const float*)d_in[11]; const float* b5 = (const float*)d_in[12];
    const float* w6 = (const float*)d_in[13]; const float* b6 = (const float*)d_in[14];
    const float* w7 = (const float*)d_in[15]; const float* b7 = (const float*)d_in[16];
    const float* wf = (const float*)d_in[17]; const float* bf = (const float*)d_in[18];
    const float* wsg= (const float*)d_in[19]; const float* bsg= (const float*)d_in[20];
    const float* wr1= (const float*)d_in[21]; const float* br1= (const float*)d_in[22];
    const float* wr2= (const float*)d_in[23]; const float* br2= (const float*)d_in[24];
    float* out = (float*)d_out;
    const int N = in_sizes[0] / 6;

    prep_weights<<<(N_FRAGS*64 + 255)/256, 256, 0, stream>>>(
        w0,w1,w2,w3,w4,w5,w6,w7,wf,wsg,wr1,wr2);
    nerf_fused<<<N/64, 256, 0, stream>>>(
        x, b0,b1,b2,b3,b4,b5,b6,b7, bf,bsg, br1,br2, out);
}